// Round 8
// baseline (61.786 us; speedup 1.0000x reference)
//
#include <hip/hip_runtime.h>

typedef __attribute__((ext_vector_type(8))) short short8;
typedef __attribute__((ext_vector_type(4))) float f32x4;

#define NRELROWS 502
#define NB 2048
#define DD 128
#define OUT_HALF (NB * DD)

__device__ __forceinline__ short f2bf(float x) {
    union { float f; unsigned u; } c; c.f = x;
    return (short)((c.u + 0x7FFFu + ((c.u >> 16) & 1u)) >> 16);
}

// Precompute: U[r][d] = sum_f rel[r][f]*W1[d][f]
//             V[r][d] = sum_f rel[r][f]*W1[d][128+f] + b1[d]
//             W2f = W2^T packed in MFMA B-fragment order, bf16
__global__ __launch_bounds__(256) void precompute_kernel(
    const float* __restrict__ rel, const float* __restrict__ W1,
    const float* __restrict__ b1, const float* __restrict__ W2,
    float* __restrict__ U, float* __restrict__ V,
    unsigned short* __restrict__ W2f)
{
    const int bid = blockIdx.x;
    const int tid = threadIdx.x;
    if (bid < 126) {
        __shared__ float srel[4][DD];
        const int r0 = bid << 2;
        for (int i = tid; i < 512; i += 256) {
            const int r = i >> 7, c = i & 127;
            const int rr = r0 + r;
            srel[r][c] = (rr < NRELROWS) ? rel[rr * DD + c] : 0.f;
        }
        __syncthreads();
        const int half = tid >> 7;      // 0 -> U, 1 -> V
        const int d = tid & 127;
        const float* wrow = W1 + d * 256 + half * 128;
        float a0 = 0.f, a1 = 0.f, a2 = 0.f, a3 = 0.f;
#pragma unroll 8
        for (int f = 0; f < 128; f += 4) {
            const float4 wv = *(const float4*)(wrow + f);
            a0 += srel[0][f]*wv.x + srel[0][f+1]*wv.y + srel[0][f+2]*wv.z + srel[0][f+3]*wv.w;
            a1 += srel[1][f]*wv.x + srel[1][f+1]*wv.y + srel[1][f+2]*wv.z + srel[1][f+3]*wv.w;
            a2 += srel[2][f]*wv.x + srel[2][f+1]*wv.y + srel[2][f+2]*wv.z + srel[2][f+3]*wv.w;
            a3 += srel[3][f]*wv.x + srel[3][f+1]*wv.y + srel[3][f+2]*wv.z + srel[3][f+3]*wv.w;
        }
        float res[4] = {a0, a1, a2, a3};
        const float bb = half ? b1[d] : 0.f;
#pragma unroll
        for (int r = 0; r < 4; ++r) {
            if (r0 + r < NRELROWS) {
                if (half) V[(r0 + r) * DD + d] = res[r] + bb;
                else      U[(r0 + r) * DD + d] = res[r];
            }
        }
    } else {
        // B-fragment packing: tile = kt*8+nt; within tile: lane ll, slot ii
        // B[f][n] with n = nt*16+(ll&15), f = kt*32+(ll>>4)*8+ii, value = W2[n][f]
        const int tile = bid - 126;   // 0..31
        const int kt = tile >> 3, nt = tile & 7;
#pragma unroll
        for (int e = 0; e < 2; ++e) {
            const int within = tid * 2 + e;          // 0..511
            const int ll = within >> 3, ii = within & 7;
            const int n = nt * 16 + (ll & 15);
            const int f = kt * 32 + (ll >> 4) * 8 + ii;
            W2f[tile * 512 + within] = (unsigned short)f2bf(W2[n * 128 + f]);
        }
    }
}

// Main: 256 blocks x 512 threads. Wave w owns query q = bid*8+w ENTIRELY:
// 8 tiles of 16 neighbor rows, double-buffered 2x8KB LDS ht slice, per-wave
// vmcnt pipeline with NO loop barriers. Counted vmcnt(8) keeps next tile's
// DMA in flight through each tile's epilogue. LDS: 8*16KB ht + 32KB W2 = 160KB.
__global__ __launch_bounds__(512, 2) void main_kernel(
    const float* __restrict__ ent, const float* __restrict__ rel,
    const float* __restrict__ off, const float* __restrict__ b2,
    const int* __restrict__ anchors, const int* __restrict__ rel0,
    const int* __restrict__ p1t, const int* __restrict__ p1r,
    const float* __restrict__ U, const float* __restrict__ V,
    const unsigned short* __restrict__ W2f, float* __restrict__ out)
{
    extern __shared__ char ldsraw[];
    const int tid = threadIdx.x;
    const int w  = __builtin_amdgcn_readfirstlane(tid >> 6);
    const int l  = tid & 63;
    const int lg = l >> 4, l15 = l & 15, hlf = l >> 5;
    unsigned short* w2l = (unsigned short*)(ldsraw + 131072);
    float* hb0 = (float*)(ldsraw + w * 16384);
    float* hb1 = (float*)(ldsraw + w * 16384 + 8192);

    const int q = (blockIdx.x << 3) + w;
    const int* p1t_q = p1t + (q << 7);
    const int* p1r_q = p1r + (q << 7);

    // ---- phase A: W2 fragment DMA (oldest vmcnt ops; wave's 4 KB share) ----
#pragma unroll
    for (int i = 0; i < 4; ++i) {
        const int chunk = (w << 2) + i;
        const unsigned short* g = W2f + chunk * 512 + (l << 3);
        unsigned short* lp = w2l + chunk * 512;
        __builtin_amdgcn_global_load_lds(
            (const __attribute__((address_space(1))) unsigned int*)g,
            (__attribute__((address_space(3))) unsigned int*)lp, 16, 0, 0);
    }
    __builtin_amdgcn_sched_barrier(0);

    // ---- phase B: t0 indices ----
    const int aidx = anchors[q];
    const int r0 = rel0[q];
    int relA = p1r_q[l15];
    int4 rr4 = *(const int4*)(p1r_q + (lg << 2));
    int rowi0[8];
#pragma unroll
    for (int j = 0; j < 8; ++j) rowi0[j] = p1t_q[(j << 1) + hlf];
    __builtin_amdgcn_sched_barrier(0);

    // ---- phase C: V (held all tiles), U(t0), persistent fragments ----
    float4 v0[4], v1[4], nu0[4], nu1[4];
    const float* Vrow = V + r0 * DD;
    const float* Urow = U + relA * DD;
#pragma unroll
    for (int kt = 0; kt < 4; ++kt) {
        const int f0 = kt * 32 + lg * 8;
        v0[kt] = *(const float4*)(Vrow + f0);
        v1[kt] = *(const float4*)(Vrow + f0 + 4);
        nu0[kt] = *(const float4*)(Urow + f0);
        nu1[kt] = *(const float4*)(Urow + f0 + 4);
    }
    float b2v[8], hav[8];
    const float* ar = ent + (size_t)aidx * DD + l15;
#pragma unroll
    for (int nt = 0; nt < 8; ++nt) {
        b2v[nt] = b2[(nt << 4) + l15];
        hav[nt] = ar[nt << 4];
    }
    __builtin_amdgcn_sched_barrier(0);

    // ---- phase D: ht DMA for t0 (newest) ----
#pragma unroll
    for (int j = 0; j < 8; ++j) {
        const float* g = ent + (size_t)rowi0[j] * DD + ((l & 31) << 2);
        float* lp = hb0 + (j << 1) * DD;
        __builtin_amdgcn_global_load_lds(
            (const __attribute__((address_space(1))) unsigned int*)g,
            (__attribute__((address_space(3))) unsigned int*)lp, 16, 0, 0);
    }
    __builtin_amdgcn_sched_barrier(0);

    // wait U/V/frags (leaves the 8 ht(t0) DMAs in flight), build af(t0)
    asm volatile("s_waitcnt vmcnt(8)" ::: "memory");
    __builtin_amdgcn_sched_barrier(0);
    short8 af[4];
#pragma unroll
    for (int kt = 0; kt < 4; ++kt) {
        af[kt][0] = f2bf(fmaxf(nu0[kt].x + v0[kt].x, 0.f));
        af[kt][1] = f2bf(fmaxf(nu0[kt].y + v0[kt].y, 0.f));
        af[kt][2] = f2bf(fmaxf(nu0[kt].z + v0[kt].z, 0.f));
        af[kt][3] = f2bf(fmaxf(nu0[kt].w + v0[kt].w, 0.f));
        af[kt][4] = f2bf(fmaxf(nu1[kt].x + v1[kt].x, 0.f));
        af[kt][5] = f2bf(fmaxf(nu1[kt].y + v1[kt].y, 0.f));
        af[kt][6] = f2bf(fmaxf(nu1[kt].z + v1[kt].z, 0.f));
        af[kt][7] = f2bf(fmaxf(nu1[kt].w + v1[kt].w, 0.f));
    }
    // w2l visibility: every wave has drained its own W2 DMA (older than its
    // U/V wait above); barrier makes all waves' chunks globally ready.
    __builtin_amdgcn_s_barrier();

    float ps[8];
#pragma unroll
    for (int nt = 0; nt < 8; ++nt) ps[nt] = 0.f;

#pragma unroll 1
    for (int t = 0; t < 8; ++t) {
        const int last = (t == 7);
        float* hbr = (t & 1) ? hb1 : hb0;
        float* hbw = (t & 1) ? hb0 : hb1;

        // --- MFMA(t): A = af regs, B = w2l ds_read (lgkm only) ---
        f32x4 acc[8];
#pragma unroll
        for (int nt = 0; nt < 8; ++nt) acc[nt] = (f32x4)0.f;
#pragma unroll
        for (int kt = 0; kt < 4; ++kt) {
#pragma unroll
            for (int nt = 0; nt < 8; ++nt) {
                const short8 bf = *(const short8*)(w2l + ((kt << 3) + nt) * 512 + (l << 3));
                acc[nt] = __builtin_amdgcn_mfma_f32_16x16x32_bf16(af[kt], bf, acc[nt], 0, 0, 0);
            }
        }
        __builtin_amdgcn_sched_barrier(0);

        // --- idx(t+1) ---
        int relA_n = 0;
        int4 rr4_n = {0, 0, 0, 0};
        int rowi_n[8];
        if (!last) {
            const int tb = (t + 1) << 4;
            relA_n = p1r_q[tb + l15];
            rr4_n = *(const int4*)(p1r_q + tb + (lg << 2));
#pragma unroll
            for (int j = 0; j < 8; ++j) rowi_n[j] = p1t_q[tb + (j << 1) + hlf];
        }
        __builtin_amdgcn_sched_barrier(0);

        // --- U(t+1) issue (consuming relA_n drains ht(t): intended) ---
        if (!last) {
            const float* Un = U + relA_n * DD;
#pragma unroll
            for (int kt = 0; kt < 4; ++kt) {
                const int f0 = kt * 32 + lg * 8;
                nu0[kt] = *(const float4*)(Un + f0);
                nu1[kt] = *(const float4*)(Un + f0 + 4);
            }
        }
        // --- rel(t) rows for epilogue ---
        float rv[4][8];
        {
            const int rrk[4] = {rr4.x, rr4.y, rr4.z, rr4.w};
#pragma unroll
            for (int r2 = 0; r2 < 4; ++r2) {
                const float* rp = rel + rrk[r2] * DD + l15;
#pragma unroll
                for (int nt = 0; nt < 8; ++nt) rv[r2][nt] = rp[nt << 4];
            }
        }
        __builtin_amdgcn_sched_barrier(0);

        // --- ht DMA (t+1) into write buffer (newest 8 vmcnt ops) ---
        if (!last) {
#pragma unroll
            for (int j = 0; j < 8; ++j) {
                const float* g = ent + (size_t)rowi_n[j] * DD + ((l & 31) << 2);
                float* lp = hbw + (j << 1) * DD;
                __builtin_amdgcn_global_load_lds(
                    (const __attribute__((address_space(1))) unsigned int*)g,
                    (__attribute__((address_space(3))) unsigned int*)lp, 16, 0, 0);
            }
        }
        __builtin_amdgcn_sched_barrier(0);

        // --- epilogue(t): drain everything except the 8 ht(t+1) DMAs ---
        if (!last) asm volatile("s_waitcnt vmcnt(8)" ::: "memory");
        else       asm volatile("s_waitcnt vmcnt(0)" ::: "memory");
        __builtin_amdgcn_sched_barrier(0);
#pragma unroll
        for (int nt = 0; nt < 8; ++nt) {
            const int d = (nt << 4) + l15;
#pragma unroll
            for (int r2 = 0; r2 < 4; ++r2) {
                const float at = acc[nt][r2] + b2v[nt];      // row lg*4+r2
                const float hv = hbr[((lg << 2) + r2) * DD + d];
                ps[nt] += at * (hv - hav[nt] - rv[r2][nt]);
            }
        }

        // --- af(t+1) from U(t+1) (already drained) + V regs ---
        if (!last) {
#pragma unroll
            for (int kt = 0; kt < 4; ++kt) {
                af[kt][0] = f2bf(fmaxf(nu0[kt].x + v0[kt].x, 0.f));
                af[kt][1] = f2bf(fmaxf(nu0[kt].y + v0[kt].y, 0.f));
                af[kt][2] = f2bf(fmaxf(nu0[kt].z + v0[kt].z, 0.f));
                af[kt][3] = f2bf(fmaxf(nu0[kt].w + v0[kt].w, 0.f));
                af[kt][4] = f2bf(fmaxf(nu1[kt].x + v1[kt].x, 0.f));
                af[kt][5] = f2bf(fmaxf(nu1[kt].y + v1[kt].y, 0.f));
                af[kt][6] = f2bf(fmaxf(nu1[kt].z + v1[kt].z, 0.f));
                af[kt][7] = f2bf(fmaxf(nu1[kt].w + v1[kt].w, 0.f));
            }
            relA = relA_n;
            rr4 = rr4_n;
        }
    }

    // ---- final reduce across lane groups + direct stores (no atomics) ----
#pragma unroll
    for (int nt = 0; nt < 8; ++nt) {
        ps[nt] += __shfl_xor(ps[nt], 16);
        ps[nt] += __shfl_xor(ps[nt], 32);
    }
    float orrv[8], offv[8];
    const float* rr0p = rel + r0 * DD + l15;
    const float* ofp  = off + r0 * DD + l15;
#pragma unroll
    for (int nt = 0; nt < 8; ++nt) {
        orrv[nt] = rr0p[nt << 4];
        offv[nt] = ofp[nt << 4];
    }
    if (lg == 0) {
#pragma unroll
        for (int nt = 0; nt < 8; ++nt)
            out[(q << 7) + (nt << 4) + l15] = hav[nt] + orrv[nt] + ps[nt];
    }
    if (lg == 1) {
#pragma unroll
        for (int nt = 0; nt < 8; ++nt)
            out[OUT_HALF + (q << 7) + (nt << 4) + l15] = offv[nt];
    }
}

extern "C" void kernel_launch(void* const* d_in, const int* in_sizes, int n_in,
                              void* d_out, int out_size, void* d_ws, size_t ws_size,
                              hipStream_t stream) {
    const float* ent  = (const float*)d_in[0];
    const float* rel  = (const float*)d_in[1];
    const float* off  = (const float*)d_in[2];
    const float* W1   = (const float*)d_in[3];
    const float* b1   = (const float*)d_in[4];
    const float* W2   = (const float*)d_in[5];
    const float* b2   = (const float*)d_in[6];
    const int* anchors = (const int*)d_in[7];
    const int* rel0    = (const int*)d_in[8];
    const int* p1t     = (const int*)d_in[9];
    const int* p1r     = (const int*)d_in[10];
    float* out = (float*)d_out;

    float* U = (float*)d_ws;                       // 502*128 f32
    float* V = U + NRELROWS * DD;                  // 502*128 f32
    unsigned short* W2f = (unsigned short*)(V + NRELROWS * DD);  // 128*128 bf16

    const int lds_bytes = 8 * 16384 + 32 * 512 * 2;   // 163840 = 160 KiB
    hipFuncSetAttribute((const void*)main_kernel,
                        hipFuncAttributeMaxDynamicSharedMemorySize, lds_bytes);

    precompute_kernel<<<126 + 32, 256, 0, stream>>>(rel, W1, b1, W2, U, V, W2f);
    main_kernel<<<NB / 8, 512, lds_bytes, stream>>>(ent, rel, off, b2, anchors, rel0,
                                                    p1t, p1r, U, V, W2f, out);
}